// Round 4
// baseline (1338.775 us; speedup 1.0000x reference)
//
#include <hip/hip_runtime.h>
#include <hip/hip_bf16.h>
#include <math.h>

// Problem: B=32, N=128, S=64, D=512
// Output: [B,N] f32, each row sorted descending.

#define BB 32
#define NN 128
#define SS 64
#define DD 512
#define NBLK 1024  // mega-kernel grid: 4 blocks/CU x 256 CUs (co-resident)

typedef __attribute__((ext_vector_type(8))) short short8;
typedef __attribute__((ext_vector_type(4))) float f32x4;

__device__ __forceinline__ ushort f2bf(float f) {
    unsigned u = __float_as_uint(f);
    unsigned r = (u + 0x7fffu + ((u >> 16) & 1u)) >> 16;
    return (ushort)r;
}

// wave(64)-cooperative dot of two 512-f32 vectors; w global, xl LDS.
__device__ __forceinline__ float wave_dot512(const float* __restrict__ w,
                                             const float* __restrict__ xl, int lane) {
    const float4* w4 = reinterpret_cast<const float4*>(w);
    const float4* x4 = reinterpret_cast<const float4*>(xl);
    float4 a0 = w4[lane * 2];
    float4 a1 = w4[lane * 2 + 1];
    float4 b0 = x4[lane * 2];
    float4 b1 = x4[lane * 2 + 1];
    float s = a0.x * b0.x + a0.y * b0.y + a0.z * b0.z + a0.w * b0.w
            + a1.x * b1.x + a1.y * b1.y + a1.z * b1.z + a1.w * b1.w;
#pragma unroll
    for (int off = 32; off; off >>= 1) s += __shfl_xor(s, off);
    return s;
}

// Two-level grid barrier: 32 group counters (64B apart) -> root -> gen.
// bar layout (uints): [grp*16] counters, [512] root, [528] gen. Zeroed per call.
__device__ __forceinline__ void gsync(unsigned* bar, int blk) {
    __syncthreads();
    if (threadIdx.x == 0) {
        unsigned* cnt = bar + (blk >> 5) * 16;
        unsigned* root = bar + 512;
        unsigned* gen = bar + 528;
        unsigned g = __hip_atomic_load(gen, __ATOMIC_RELAXED, __HIP_MEMORY_SCOPE_AGENT);
        bool last = false;
        if (__hip_atomic_fetch_add(cnt, 1u, __ATOMIC_ACQ_REL,
                                   __HIP_MEMORY_SCOPE_AGENT) == 31u) {
            if (__hip_atomic_fetch_add(root, 1u, __ATOMIC_ACQ_REL,
                                       __HIP_MEMORY_SCOPE_AGENT) == 31u) {
                // global last: reset counters, then release new generation
                for (int i = 0; i < 32; ++i)
                    __hip_atomic_store(bar + i * 16, 0u, __ATOMIC_RELAXED,
                                       __HIP_MEMORY_SCOPE_AGENT);
                __hip_atomic_store(root, 0u, __ATOMIC_RELAXED,
                                   __HIP_MEMORY_SCOPE_AGENT);
                __hip_atomic_fetch_add(gen, 1u, __ATOMIC_RELEASE,
                                       __HIP_MEMORY_SCOPE_AGENT);
                last = true;
            }
        }
        if (!last) {
            while (__hip_atomic_load(gen, __ATOMIC_ACQUIRE,
                                     __HIP_MEMORY_SCOPE_AGENT) == g)
                __builtin_amdgcn_s_sleep(1);
        }
    }
    __syncthreads();
}

// Mega-kernel: 8 stages with 7 grid syncs. Grid exactly NBLK=1024 blocks.
__global__ __launch_bounds__(256, 4) void mega(
    const int* __restrict__ ts, const float* __restrict__ pe,
    const float* __restrict__ fusion, const float* __restrict__ tif,
    const float* __restrict__ x,
    const float* __restrict__ Wt1, const float* __restrict__ bt1,
    const float* __restrict__ Wt2, const float* __restrict__ bt2,
    const float* __restrict__ Wq, const float* __restrict__ Wk,
    const float* __restrict__ Wv, const float* __restrict__ Wp,
    const float* __restrict__ bp, const float* __restrict__ Wd1,
    float* __restrict__ cond, float* __restrict__ qk,
    float* __restrict__ h, float* __restrict__ q,
    float* __restrict__ wout, float* __restrict__ vsum,
    float* __restrict__ ve, float* __restrict__ ne,
    float* __restrict__ tif_best, ushort* __restrict__ abf,
    ushort* __restrict__ Wb, unsigned* __restrict__ bar) {
    int blk = blockIdx.x, tid = threadIdx.x, lane = tid & 63, wave = tid >> 6;
    __shared__ __align__(16) float xl[DD];
    __shared__ __align__(16) float aux[4][64];
    __shared__ float sc[NN], wl[NN];
    __shared__ float redf[8];
    __shared__ int redi[4];
    __shared__ int bidx_s;

    int b5 = blk & 31, c5 = blk >> 5;  // standard (b, chunk) mapping

    // ---- S1: h = silu(Wt1 @ pe[ts[b]] + bt1)  (1024 jobs)  +  convWb spread
    {
        const float* src = pe + (size_t)ts[b5] * DD;
        for (int i = tid; i < DD; i += 256) xl[i] = src[i];
        __syncthreads();
        int j0 = c5 * 16 + wave * 4;
#pragma unroll
        for (int jj = 0; jj < 4; ++jj) {
            int j = j0 + jj;
            float s = wave_dot512(Wt1 + (size_t)j * DD, xl, lane) + bt1[j];
            if (lane == 0) h[(size_t)b5 * DD + j] = s / (1.f + expf(-s));
        }
        // convWb: Wb[r][k] = bf16(Wd1[r][512+k]); 2 elems/thread across grid
        int idx = (blk * 256 + tid) * 2;  // 0 .. 524286
        int r = idx >> 9, k = idx & 511;
        float2 v = *reinterpret_cast<const float2*>(Wd1 + (size_t)r * 1024 + 512 + k);
        ushort2 o = {f2bf(v.x), f2bf(v.y)};
        *reinterpret_cast<ushort2*>(Wb + (size_t)r * 512 + k) = o;
    }
    gsync(bar, blk);

    // ---- S2: cond = Wt2 @ h + bt2
    {
        const float* src = h + (size_t)b5 * DD;
        for (int i = tid; i < DD; i += 256) xl[i] = src[i];
        __syncthreads();
        int j0 = c5 * 16 + wave * 4;
#pragma unroll
        for (int jj = 0; jj < 4; ++jj) {
            int j = j0 + jj;
            float s = wave_dot512(Wt2 + (size_t)j * DD, xl, lane) + bt2[j];
            if (lane == 0) cond[(size_t)b5 * DD + j] = s;
        }
    }
    gsync(bar, blk);

    // ---- S3: q = Wq @ (fusion + cond)
    {
        const float* sa = fusion + (size_t)b5 * DD;
        const float* sb = cond + (size_t)b5 * DD;
        for (int i = tid; i < DD; i += 256) xl[i] = sa[i] + sb[i];
        __syncthreads();
        int j0 = c5 * 16 + wave * 4;
#pragma unroll
        for (int jj = 0; jj < 4; ++jj) {
            int j = j0 + jj;
            float s = wave_dot512(Wq + (size_t)j * DD, xl, lane);
            if (lane == 0) q[(size_t)b5 * DD + j] = s;
        }
    }
    gsync(bar, blk);

    // ---- S4: qk = Wk^T @ q   (256 jobs: 8 col-chunks x 32 b)
    if (blk < 256) {
        int b = blk & 31, c0 = (blk >> 5) * 64;
        for (int i = tid; i < DD; i += 256) xl[i] = q[(size_t)b * DD + i];
        __syncthreads();
        float p = 0.f;
        for (int j = wave * 128; j < wave * 128 + 128; ++j)
            p += xl[j] * Wk[(size_t)j * DD + c0 + lane];
        aux[wave][lane] = p;
        __syncthreads();
        if (tid < 64)
            qk[(size_t)b * DD + c0 + tid] =
                aux[0][tid] + aux[1][tid] + aux[2][tid] + aux[3][tid];
    }
    gsync(bar, blk);

    // ---- S5: k2 — sim argmax + gather (f32 + bf16). 4096 jobs, stride NBLK.
    for (int job = blk; job < BB * NN; job += NBLK) {
        int b = job >> 7;
        __syncthreads();  // protect xl reuse across jobs
        for (int i = tid; i < DD; i += 256) xl[i] = fusion[(size_t)b * DD + i];
        __syncthreads();
        const float* base = tif + (size_t)job * SS * DD;
        float bv = -INFINITY;
        int bi = 0;
        for (int s = wave * 16; s < wave * 16 + 16; ++s) {
            float v = wave_dot512(base + (size_t)s * DD, xl, lane);
            if (v > bv) { bv = v; bi = s; }  // strict > keeps first (np.argmax)
        }
        if (lane == 0) { redf[wave] = bv; redi[wave] = bi; }
        __syncthreads();
        if (tid == 0) {
            float v = redf[0]; int i0 = redi[0];
            for (int w2 = 1; w2 < 4; ++w2)
                if (redf[w2] > v) { v = redf[w2]; i0 = redi[w2]; }
            bidx_s = i0;
        }
        __syncthreads();
        const float* src = base + (size_t)bidx_s * DD;
        for (int i = tid; i < DD; i += 256) {
            float vv = src[i];
            tif_best[(size_t)job * DD + i] = vv;
            abf[(size_t)job * DD + i] = f2bf(vv);
        }
    }
    gsync(bar, blk);

    // ---- S6: score + softmax + vsum + wout  (32 jobs, one per b)
    if (blk < 32) {
        int b = blk;
        for (int i = tid; i < DD; i += 256) xl[i] = qk[(size_t)b * DD + i];
        __syncthreads();
        for (int n = wave * 32; n < wave * 32 + 32; ++n) {
            float s = wave_dot512(tif_best + ((size_t)(b * NN + n)) * DD, xl, lane);
            if (lane == 0) sc[n] = s + x[b * NN + n];
        }
        __syncthreads();
        float v = 0.f;
        if (tid < NN) {
            v = sc[tid];
            float m = v;
#pragma unroll
            for (int off = 32; off; off >>= 1) m = fmaxf(m, __shfl_xor(m, off));
            if (lane == 0) redf[wave] = m;
        }
        __syncthreads();
        float m = fmaxf(redf[0], redf[1]);
        if (tid < NN) {
            float e = expf(v - m);
            wl[tid] = e;
            float s = e;
#pragma unroll
            for (int off = 32; off; off >>= 1) s += __shfl_xor(s, off);
            if (lane == 0) redf[4 + wave] = s;
        }
        __syncthreads();
        float inv = 1.f / (redf[4] + redf[5]);
        if (tid < NN) { wl[tid] *= inv; wout[b * NN + tid] = wl[tid]; }
        __syncthreads();
#pragma unroll
        for (int half = 0; half < 2; ++half) {
            int d = tid + half * 256;
            const float* base = tif_best + (size_t)b * NN * DD + d;
            float s = 0.f;
#pragma unroll 8
            for (int n = 0; n < NN; n++) s += wl[n] * base[(size_t)n * DD];
            vsum[(size_t)b * DD + d] = s + cond[(size_t)b * DD + d];
        }
    }
    gsync(bar, blk);

    // ---- S7: ve = Wv @ vsum
    {
        const float* src = vsum + (size_t)b5 * DD;
        for (int i = tid; i < DD; i += 256) xl[i] = src[i];
        __syncthreads();
        int j0 = c5 * 16 + wave * 4;
#pragma unroll
        for (int jj = 0; jj < 4; ++jj) {
            int j = j0 + jj;
            float s = wave_dot512(Wv + (size_t)j * DD, xl, lane);
            if (lane == 0) ve[(size_t)b5 * DD + j] = s;
        }
    }
    gsync(bar, blk);

    // ---- S8: ne = Wp @ ve + bp
    {
        const float* src = ve + (size_t)b5 * DD;
        for (int i = tid; i < DD; i += 256) xl[i] = src[i];
        __syncthreads();
        int j0 = c5 * 16 + wave * 4;
#pragma unroll
        for (int jj = 0; jj < 4; ++jj) {
            int j = j0 + jj;
            float s = wave_dot512(Wp + (size_t)j * DD, xl, lane) + bp[j];
            if (lane == 0) ne[(size_t)b5 * DD + j] = s;
        }
    }
}

// K4: bf16 MFMA GEMM  C[4096,1024] = Abf[4096,512] x Wb^T, fused u + relu + Wd2.
// Prologue computes this block's 128-row u-slice: u[r] = Wd1_a[r].ne[b] + bd1[r].
__global__ __launch_bounds__(256) void k4_mfma(
    const ushort* __restrict__ Abf, const ushort* __restrict__ Wb,
    const float* __restrict__ Wd1, const float* __restrict__ bd1,
    const float* __restrict__ ne, const float* __restrict__ Wd2,
    float* __restrict__ p_part) {
    __shared__ ushort aS[128 * 64];  // 16 KB
    __shared__ ushort bS[128 * 64];
    __shared__ __align__(16) float nel[DD];
    __shared__ float uloc[128];
    int tid = threadIdx.x, l = tid & 63, w = tid >> 6;
    int m0 = blockIdx.x * 128, n0 = blockIdx.y * 128;
    int b = blockIdx.x;  // BM=128 == N rows per batch
    int wm = w >> 1, wn = w & 1;

    for (int i = tid; i < DD; i += 256) nel[i] = ne[(size_t)b * DD + i];
    __syncthreads();
    for (int rr = wave_dot512 ? 0 : 0, r = w * 32; r < w * 32 + 32; ++r) {
        float s = wave_dot512(Wd1 + (size_t)(n0 + r) * 1024, nel, l) + bd1[n0 + r];
        if (l == 0) uloc[r] = s;
    }

    f32x4 acc[4][4];
#pragma unroll
    for (int i = 0; i < 4; i++)
#pragma unroll
        for (int j = 0; j < 4; j++) acc[i][j] = (f32x4){0.f, 0.f, 0.f, 0.f};

    for (int k0 = 0; k0 < DD; k0 += 64) {
#pragma unroll
        for (int i = 0; i < 4; ++i) {
            int L = i * 4096 + w * 1024 + l * 16;  // linear byte in 16KB tile
            int row = L >> 7;
            int bo = L & 127;
            int sb = bo ^ ((row & 7) << 4);  // pre-swizzled source
            const ushort* ga = Abf + (size_t)(m0 + row) * DD + k0 + (sb >> 1);
            const ushort* gb = Wb + (size_t)(n0 + row) * DD + k0 + (sb >> 1);
            __builtin_amdgcn_global_load_lds(
                (const __attribute__((address_space(1))) void*)ga,
                (__attribute__((address_space(3))) void*)(aS + i * 2048 + w * 512),
                16, 0, 0);
            __builtin_amdgcn_global_load_lds(
                (const __attribute__((address_space(1))) void*)gb,
                (__attribute__((address_space(3))) void*)(bS + i * 2048 + w * 512),
                16, 0, 0);
        }
        __syncthreads();
#pragma unroll
        for (int kk = 0; kk < 2; ++kk) {
            short8 af[4], bf[4];
#pragma unroll
            for (int f = 0; f < 4; ++f) {
                int ra = wm * 64 + f * 16 + (l & 15);
                int boa = (((l >> 4) * 16 + kk * 64)) ^ ((ra & 7) << 4);
                af[f] = *reinterpret_cast<const short8*>(&aS[ra * 64 + (boa >> 1)]);
                int rb = wn * 64 + f * 16 + (l & 15);
                int bob = (((l >> 4) * 16 + kk * 64)) ^ ((rb & 7) << 4);
                bf[f] = *reinterpret_cast<const short8*>(&bS[rb * 64 + (bob >> 1)]);
            }
#pragma unroll
            for (int fm = 0; fm < 4; ++fm)
#pragma unroll
                for (int fn = 0; fn < 4; ++fn)
                    acc[fm][fn] = __builtin_amdgcn_mfma_f32_16x16x32_bf16(
                        af[fm], bf[fn], acc[fm][fn], 0, 0, 0);
        }
        __syncthreads();
    }
#pragma unroll
    for (int fm = 0; fm < 4; ++fm) {
#pragma unroll
        for (int reg = 0; reg < 4; ++reg) {
            float pp = 0.f;
#pragma unroll
            for (int fn = 0; fn < 4; ++fn) {
                int rl = wn * 64 + fn * 16 + (l & 15);
                float hh = acc[fm][fn][reg] + uloc[rl];
                if (hh > 0.f) pp += Wd2[n0 + rl] * hh;
            }
#pragma unroll
            for (int off = 1; off < 16; off <<= 1) pp += __shfl_xor(pp, off);
            if ((l & 15) == 0) {
                int m = m0 + wm * 64 + fm * 16 + (l >> 4) * 4 + reg;
                p_part[(size_t)m * 16 + blockIdx.y * 2 + wn] = pp;
            }
        }
    }
}

// K5: p = sum(p_part) + bd2 + w; bitonic sort 128 descending per b.
__global__ __launch_bounds__(128) void k5_sort(
    const float* __restrict__ p_part, const float* __restrict__ wout,
    const float* __restrict__ bd2, float* __restrict__ out) {
    __shared__ float v[NN];
    int b = blockIdx.x, tid = threadIdx.x;
    int bn = b * NN + tid;
    float s = bd2[0] + wout[bn];
#pragma unroll
    for (int c = 0; c < 16; c++) s += p_part[(size_t)bn * 16 + c];
    v[tid] = s;
    __syncthreads();
    for (int k = 2; k <= NN; k <<= 1) {
        for (int j = k >> 1; j > 0; j >>= 1) {
            int ixj = tid ^ j;
            if (ixj > tid) {
                float a = v[tid], bb2 = v[ixj];
                bool desc = (tid & k) == 0;
                if (desc ? (a < bb2) : (a > bb2)) { v[tid] = bb2; v[ixj] = a; }
            }
            __syncthreads();
        }
    }
    out[bn] = v[tid];
}

extern "C" void kernel_launch(void* const* d_in, const int* in_sizes, int n_in,
                              void* d_out, int out_size, void* d_ws, size_t ws_size,
                              hipStream_t stream) {
    const float* x      = (const float*)d_in[0];
    const int*   ts     = (const int*)d_in[1];
    const float* fusion = (const float*)d_in[2];
    const float* tif    = (const float*)d_in[3];
    const float* pe     = (const float*)d_in[4];
    const float* Wq     = (const float*)d_in[5];
    const float* Wk     = (const float*)d_in[6];
    const float* Wv     = (const float*)d_in[7];
    const float* Wp     = (const float*)d_in[8];
    const float* bp     = (const float*)d_in[9];
    const float* Wt1    = (const float*)d_in[10];
    const float* bt1    = (const float*)d_in[11];
    const float* Wt2    = (const float*)d_in[12];
    const float* bt2    = (const float*)d_in[13];
    const float* Wd1    = (const float*)d_in[14];
    const float* bd1    = (const float*)d_in[15];
    const float* Wd2    = (const float*)d_in[16];
    const float* bd2    = (const float*)d_in[17];

    float* ws = (float*)d_ws;
    float* cond     = ws;                    // 16384
    float* qk       = cond + 16384;          // 16384
    float* h        = qk + 16384;            // 16384
    float* q        = h + 16384;             // 16384
    float* wout     = q + 16384;             // 4096
    float* vsum     = wout + 4096;           // 16384
    float* ve       = vsum + 16384;          // 16384
    float* ne       = ve + 16384;            // 16384
    float* p_part   = ne + 16384;            // 65536
    float* tif_best = p_part + 65536;        // 2097152 (8 MB)
    ushort* Abf     = (ushort*)(tif_best + 2097152);  // 4 MB
    ushort* Wb      = Abf + 2097152;         // 1 MB
    unsigned* bar   = (unsigned*)(Wb + 524288);  // 4 KB barrier area
    float* out = (float*)d_out;

    hipMemsetAsync(bar, 0, 4096, stream);
    hipLaunchKernelGGL(mega, dim3(NBLK), dim3(256), 0, stream,
                       ts, pe, fusion, tif, x,
                       Wt1, bt1, Wt2, bt2, Wq, Wk, Wv, Wp, bp, Wd1,
                       cond, qk, h, q, wout, vsum, ve, ne,
                       tif_best, Abf, Wb, bar);
    hipLaunchKernelGGL(k4_mfma, dim3(32, 8), dim3(256), 0, stream,
                       Abf, Wb, Wd1, bd1, ne, Wd2, p_part);
    hipLaunchKernelGGL(k5_sort, dim3(BB), dim3(128), 0, stream,
                       p_part, wout, bd2, out);
}

// Round 5
// 466.917 us; speedup vs baseline: 2.8673x; 2.8673x over previous
//
#include <hip/hip_runtime.h>
#include <hip/hip_bf16.h>
#include <math.h>

// Problem: B=32, N=128, S=64, D=512
// Output: [B,N] f32, each row sorted descending.

#define BB 32
#define NN 128
#define SS 64
#define DD 512
#define NBLK 1024  // mega-kernel grid: 4 blocks/CU x 256 CUs (co-resident)

typedef __attribute__((ext_vector_type(8))) short short8;
typedef __attribute__((ext_vector_type(4))) float f32x4;

__device__ __forceinline__ ushort f2bf(float f) {
    unsigned u = __float_as_uint(f);
    unsigned r = (u + 0x7fffu + ((u >> 16) & 1u)) >> 16;
    return (ushort)r;
}

// wave(64)-cooperative dot of two 512-f32 vectors; w global, xl LDS.
__device__ __forceinline__ float wave_dot512(const float* __restrict__ w,
                                             const float* __restrict__ xl, int lane) {
    const float4* w4 = reinterpret_cast<const float4*>(w);
    const float4* x4 = reinterpret_cast<const float4*>(xl);
    float4 a0 = w4[lane * 2];
    float4 a1 = w4[lane * 2 + 1];
    float4 b0 = x4[lane * 2];
    float4 b1 = x4[lane * 2 + 1];
    float s = a0.x * b0.x + a0.y * b0.y + a0.z * b0.z + a0.w * b0.w
            + a1.x * b1.x + a1.y * b1.y + a1.z * b1.z + a1.w * b1.w;
#pragma unroll
    for (int off = 32; off; off >>= 1) s += __shfl_xor(s, off);
    return s;
}

// Two-level grid barrier. CRITICAL (round-4 lesson): the spin poll must be
// RELAXED (agent-scope relaxed loads bypass L2 for coherence but do NOT
// invalidate it); a single ACQUIRE fence after the spin provides ordering.
// An ACQUIRE *inside* the poll loop emits buffer_inv per iteration -> chip-
// wide L2-invalidate storm -> 10x slowdown (measured round 4).
__device__ __forceinline__ void gsync(unsigned* bar, int blk) {
    __syncthreads();
    if (threadIdx.x == 0) {
        unsigned* cnt = bar + (blk >> 5) * 16;
        unsigned* root = bar + 512;
        unsigned* gen = bar + 528;
        unsigned g = __hip_atomic_load(gen, __ATOMIC_RELAXED, __HIP_MEMORY_SCOPE_AGENT);
        bool last = false;
        if (__hip_atomic_fetch_add(cnt, 1u, __ATOMIC_ACQ_REL,
                                   __HIP_MEMORY_SCOPE_AGENT) == 31u) {
            if (__hip_atomic_fetch_add(root, 1u, __ATOMIC_ACQ_REL,
                                       __HIP_MEMORY_SCOPE_AGENT) == 31u) {
                // global last: reset counters, then release new generation
                for (int i = 0; i < 32; ++i)
                    __hip_atomic_store(bar + i * 16, 0u, __ATOMIC_RELAXED,
                                       __HIP_MEMORY_SCOPE_AGENT);
                __hip_atomic_store(root, 0u, __ATOMIC_RELAXED,
                                   __HIP_MEMORY_SCOPE_AGENT);
                __hip_atomic_fetch_add(gen, 1u, __ATOMIC_RELEASE,
                                       __HIP_MEMORY_SCOPE_AGENT);
                last = true;
            }
        }
        if (!last) {
            while (__hip_atomic_load(gen, __ATOMIC_RELAXED,
                                     __HIP_MEMORY_SCOPE_AGENT) == g)
                __builtin_amdgcn_s_sleep(8);
            __builtin_amdgcn_fence(__ATOMIC_ACQUIRE, "agent");
        }
    }
    __syncthreads();
}

// Mega-kernel: 8 stages with 7 grid syncs. Grid exactly NBLK=1024 blocks.
__global__ __launch_bounds__(256, 4) void mega(
    const int* __restrict__ ts, const float* __restrict__ pe,
    const float* __restrict__ fusion, const float* __restrict__ tif,
    const float* __restrict__ x,
    const float* __restrict__ Wt1, const float* __restrict__ bt1,
    const float* __restrict__ Wt2, const float* __restrict__ bt2,
    const float* __restrict__ Wq, const float* __restrict__ Wk,
    const float* __restrict__ Wv, const float* __restrict__ Wp,
    const float* __restrict__ bp, const float* __restrict__ Wd1,
    float* __restrict__ cond, float* __restrict__ qk,
    float* __restrict__ h, float* __restrict__ q,
    float* __restrict__ wout, float* __restrict__ vsum,
    float* __restrict__ ve, float* __restrict__ ne,
    float* __restrict__ tif_best, ushort* __restrict__ abf,
    ushort* __restrict__ Wb, unsigned* __restrict__ bar) {
    int blk = blockIdx.x, tid = threadIdx.x, lane = tid & 63, wave = tid >> 6;
    __shared__ __align__(16) float xl[DD];
    __shared__ __align__(16) float aux[4][64];
    __shared__ float sc[NN], wl[NN];
    __shared__ float redf[8];
    __shared__ int redi[4];
    __shared__ int bidx_s;

    int b5 = blk & 31, c5 = blk >> 5;  // standard (b, chunk) mapping

    // ---- S1: h = silu(Wt1 @ pe[ts[b]] + bt1)  (1024 jobs)  +  convWb spread
    {
        const float* src = pe + (size_t)ts[b5] * DD;
        for (int i = tid; i < DD; i += 256) xl[i] = src[i];
        __syncthreads();
        int j0 = c5 * 16 + wave * 4;
#pragma unroll
        for (int jj = 0; jj < 4; ++jj) {
            int j = j0 + jj;
            float s = wave_dot512(Wt1 + (size_t)j * DD, xl, lane) + bt1[j];
            if (lane == 0) h[(size_t)b5 * DD + j] = s / (1.f + expf(-s));
        }
        // convWb: Wb[r][k] = bf16(Wd1[r][512+k]); 2 elems/thread across grid
        int idx = (blk * 256 + tid) * 2;  // 0 .. 524286
        int r = idx >> 9, k = idx & 511;
        float2 v = *reinterpret_cast<const float2*>(Wd1 + (size_t)r * 1024 + 512 + k);
        ushort2 o = {f2bf(v.x), f2bf(v.y)};
        *reinterpret_cast<ushort2*>(Wb + (size_t)r * 512 + k) = o;
    }
    gsync(bar, blk);

    // ---- S2: cond = Wt2 @ h + bt2
    {
        const float* src = h + (size_t)b5 * DD;
        for (int i = tid; i < DD; i += 256) xl[i] = src[i];
        __syncthreads();
        int j0 = c5 * 16 + wave * 4;
#pragma unroll
        for (int jj = 0; jj < 4; ++jj) {
            int j = j0 + jj;
            float s = wave_dot512(Wt2 + (size_t)j * DD, xl, lane) + bt2[j];
            if (lane == 0) cond[(size_t)b5 * DD + j] = s;
        }
    }
    gsync(bar, blk);

    // ---- S3: q = Wq @ (fusion + cond)
    {
        const float* sa = fusion + (size_t)b5 * DD;
        const float* sb = cond + (size_t)b5 * DD;
        for (int i = tid; i < DD; i += 256) xl[i] = sa[i] + sb[i];
        __syncthreads();
        int j0 = c5 * 16 + wave * 4;
#pragma unroll
        for (int jj = 0; jj < 4; ++jj) {
            int j = j0 + jj;
            float s = wave_dot512(Wq + (size_t)j * DD, xl, lane);
            if (lane == 0) q[(size_t)b5 * DD + j] = s;
        }
    }
    gsync(bar, blk);

    // ---- S4: qk = Wk^T @ q   (256 jobs: 8 col-chunks x 32 b)
    if (blk < 256) {
        int b = blk & 31, c0 = (blk >> 5) * 64;
        for (int i = tid; i < DD; i += 256) xl[i] = q[(size_t)b * DD + i];
        __syncthreads();
        float p = 0.f;
        for (int j = wave * 128; j < wave * 128 + 128; ++j)
            p += xl[j] * Wk[(size_t)j * DD + c0 + lane];
        aux[wave][lane] = p;
        __syncthreads();
        if (tid < 64)
            qk[(size_t)b * DD + c0 + tid] =
                aux[0][tid] + aux[1][tid] + aux[2][tid] + aux[3][tid];
    }
    gsync(bar, blk);

    // ---- S5: k2 — sim argmax + gather (f32 + bf16). 4096 jobs, stride NBLK.
    for (int job = blk; job < BB * NN; job += NBLK) {
        int b = job >> 7;
        __syncthreads();  // protect xl reuse across jobs
        for (int i = tid; i < DD; i += 256) xl[i] = fusion[(size_t)b * DD + i];
        __syncthreads();
        const float* base = tif + (size_t)job * SS * DD;
        float bv = -INFINITY;
        int bi = 0;
        for (int s = wave * 16; s < wave * 16 + 16; ++s) {
            float v = wave_dot512(base + (size_t)s * DD, xl, lane);
            if (v > bv) { bv = v; bi = s; }  // strict > keeps first (np.argmax)
        }
        if (lane == 0) { redf[wave] = bv; redi[wave] = bi; }
        __syncthreads();
        if (tid == 0) {
            float v = redf[0]; int i0 = redi[0];
            for (int w2 = 1; w2 < 4; ++w2)
                if (redf[w2] > v) { v = redf[w2]; i0 = redi[w2]; }
            bidx_s = i0;
        }
        __syncthreads();
        const float* src = base + (size_t)bidx_s * DD;
        for (int i = tid; i < DD; i += 256) {
            float vv = src[i];
            tif_best[(size_t)job * DD + i] = vv;
            abf[(size_t)job * DD + i] = f2bf(vv);
        }
    }
    gsync(bar, blk);

    // ---- S6: score + softmax + vsum + wout  (32 jobs, one per b)
    if (blk < 32) {
        int b = blk;
        for (int i = tid; i < DD; i += 256) xl[i] = qk[(size_t)b * DD + i];
        __syncthreads();
        for (int n = wave * 32; n < wave * 32 + 32; ++n) {
            float s = wave_dot512(tif_best + ((size_t)(b * NN + n)) * DD, xl, lane);
            if (lane == 0) sc[n] = s + x[b * NN + n];
        }
        __syncthreads();
        float v = 0.f;
        if (tid < NN) {
            v = sc[tid];
            float m = v;
#pragma unroll
            for (int off = 32; off; off >>= 1) m = fmaxf(m, __shfl_xor(m, off));
            if (lane == 0) redf[wave] = m;
        }
        __syncthreads();
        float m = fmaxf(redf[0], redf[1]);
        if (tid < NN) {
            float e = expf(v - m);
            wl[tid] = e;
            float s = e;
#pragma unroll
            for (int off = 32; off; off >>= 1) s += __shfl_xor(s, off);
            if (lane == 0) redf[4 + wave] = s;
        }
        __syncthreads();
        float inv = 1.f / (redf[4] + redf[5]);
        if (tid < NN) { wl[tid] *= inv; wout[b * NN + tid] = wl[tid]; }
        __syncthreads();
#pragma unroll
        for (int half = 0; half < 2; ++half) {
            int d = tid + half * 256;
            const float* base = tif_best + (size_t)b * NN * DD + d;
            float s = 0.f;
#pragma unroll 8
            for (int n = 0; n < NN; n++) s += wl[n] * base[(size_t)n * DD];
            vsum[(size_t)b * DD + d] = s + cond[(size_t)b * DD + d];
        }
    }
    gsync(bar, blk);

    // ---- S7: ve = Wv @ vsum
    {
        const float* src = vsum + (size_t)b5 * DD;
        for (int i = tid; i < DD; i += 256) xl[i] = src[i];
        __syncthreads();
        int j0 = c5 * 16 + wave * 4;
#pragma unroll
        for (int jj = 0; jj < 4; ++jj) {
            int j = j0 + jj;
            float s = wave_dot512(Wv + (size_t)j * DD, xl, lane);
            if (lane == 0) ve[(size_t)b5 * DD + j] = s;
        }
    }
    gsync(bar, blk);

    // ---- S8: ne = Wp @ ve + bp
    {
        const float* src = ve + (size_t)b5 * DD;
        for (int i = tid; i < DD; i += 256) xl[i] = src[i];
        __syncthreads();
        int j0 = c5 * 16 + wave * 4;
#pragma unroll
        for (int jj = 0; jj < 4; ++jj) {
            int j = j0 + jj;
            float s = wave_dot512(Wp + (size_t)j * DD, xl, lane) + bp[j];
            if (lane == 0) ne[(size_t)b5 * DD + j] = s;
        }
    }
}

// K4: bf16 MFMA GEMM  C[4096,1024] = Abf[4096,512] x Wb^T, fused u + relu + Wd2.
// Prologue computes this block's 128-row u-slice: u[r] = Wd1_a[r].ne[b] + bd1[r].
__global__ __launch_bounds__(256) void k4_mfma(
    const ushort* __restrict__ Abf, const ushort* __restrict__ Wb,
    const float* __restrict__ Wd1, const float* __restrict__ bd1,
    const float* __restrict__ ne, const float* __restrict__ Wd2,
    float* __restrict__ p_part) {
    __shared__ ushort aS[128 * 64];  // 16 KB
    __shared__ ushort bS[128 * 64];
    __shared__ __align__(16) float nel[DD];
    __shared__ float uloc[128];
    int tid = threadIdx.x, l = tid & 63, w = tid >> 6;
    int m0 = blockIdx.x * 128, n0 = blockIdx.y * 128;
    int b = blockIdx.x;  // BM=128 == N rows per batch
    int wm = w >> 1, wn = w & 1;

    for (int i = tid; i < DD; i += 256) nel[i] = ne[(size_t)b * DD + i];
    __syncthreads();
    for (int r = w * 32; r < w * 32 + 32; ++r) {
        float s = wave_dot512(Wd1 + (size_t)(n0 + r) * 1024, nel, l) + bd1[n0 + r];
        if (l == 0) uloc[r] = s;
    }

    f32x4 acc[4][4];
#pragma unroll
    for (int i = 0; i < 4; i++)
#pragma unroll
        for (int j = 0; j < 4; j++) acc[i][j] = (f32x4){0.f, 0.f, 0.f, 0.f};

    for (int k0 = 0; k0 < DD; k0 += 64) {
#pragma unroll
        for (int i = 0; i < 4; ++i) {
            int L = i * 4096 + w * 1024 + l * 16;  // linear byte in 16KB tile
            int row = L >> 7;
            int bo = L & 127;
            int sb = bo ^ ((row & 7) << 4);  // pre-swizzled source
            const ushort* ga = Abf + (size_t)(m0 + row) * DD + k0 + (sb >> 1);
            const ushort* gb = Wb + (size_t)(n0 + row) * DD + k0 + (sb >> 1);
            __builtin_amdgcn_global_load_lds(
                (const __attribute__((address_space(1))) void*)ga,
                (__attribute__((address_space(3))) void*)(aS + i * 2048 + w * 512),
                16, 0, 0);
            __builtin_amdgcn_global_load_lds(
                (const __attribute__((address_space(1))) void*)gb,
                (__attribute__((address_space(3))) void*)(bS + i * 2048 + w * 512),
                16, 0, 0);
        }
        __syncthreads();
#pragma unroll
        for (int kk = 0; kk < 2; ++kk) {
            short8 af[4], bf[4];
#pragma unroll
            for (int f = 0; f < 4; ++f) {
                int ra = wm * 64 + f * 16 + (l & 15);
                int boa = (((l >> 4) * 16 + kk * 64)) ^ ((ra & 7) << 4);
                af[f] = *reinterpret_cast<const short8*>(&aS[ra * 64 + (boa >> 1)]);
                int rb = wn * 64 + f * 16 + (l & 15);
                int bob = (((l >> 4) * 16 + kk * 64)) ^ ((rb & 7) << 4);
                bf[f] = *reinterpret_cast<const short8*>(&bS[rb * 64 + (bob >> 1)]);
            }
#pragma unroll
            for (int fm = 0; fm < 4; ++fm)
#pragma unroll
                for (int fn = 0; fn < 4; ++fn)
                    acc[fm][fn] = __builtin_amdgcn_mfma_f32_16x16x32_bf16(
                        af[fm], bf[fn], acc[fm][fn], 0, 0, 0);
        }
        __syncthreads();
    }
#pragma unroll
    for (int fm = 0; fm < 4; ++fm) {
#pragma unroll
        for (int reg = 0; reg < 4; ++reg) {
            float pp = 0.f;
#pragma unroll
            for (int fn = 0; fn < 4; ++fn) {
                int rl = wn * 64 + fn * 16 + (l & 15);
                float hh = acc[fm][fn][reg] + uloc[rl];
                if (hh > 0.f) pp += Wd2[n0 + rl] * hh;
            }
#pragma unroll
            for (int off = 1; off < 16; off <<= 1) pp += __shfl_xor(pp, off);
            if ((l & 15) == 0) {
                int m = m0 + wm * 64 + fm * 16 + (l >> 4) * 4 + reg;
                p_part[(size_t)m * 16 + blockIdx.y * 2 + wn] = pp;
            }
        }
    }
}

// K5: p = sum(p_part) + bd2 + w; bitonic sort 128 descending per b.
__global__ __launch_bounds__(128) void k5_sort(
    const float* __restrict__ p_part, const float* __restrict__ wout,
    const float* __restrict__ bd2, float* __restrict__ out) {
    __shared__ float v[NN];
    int b = blockIdx.x, tid = threadIdx.x;
    int bn = b * NN + tid;
    float s = bd2[0] + wout[bn];
#pragma unroll
    for (int c = 0; c < 16; c++) s += p_part[(size_t)bn * 16 + c];
    v[tid] = s;
    __syncthreads();
    for (int k = 2; k <= NN; k <<= 1) {
        for (int j = k >> 1; j > 0; j >>= 1) {
            int ixj = tid ^ j;
            if (ixj > tid) {
                float a = v[tid], bb2 = v[ixj];
                bool desc = (tid & k) == 0;
                if (desc ? (a < bb2) : (a > bb2)) { v[tid] = bb2; v[ixj] = a; }
            }
            __syncthreads();
        }
    }
    out[bn] = v[tid];
}

extern "C" void kernel_launch(void* const* d_in, const int* in_sizes, int n_in,
                              void* d_out, int out_size, void* d_ws, size_t ws_size,
                              hipStream_t stream) {
    const float* x      = (const float*)d_in[0];
    const int*   ts     = (const int*)d_in[1];
    const float* fusion = (const float*)d_in[2];
    const float* tif    = (const float*)d_in[3];
    const float* pe     = (const float*)d_in[4];
    const float* Wq     = (const float*)d_in[5];
    const float* Wk     = (const float*)d_in[6];
    const float* Wv     = (const float*)d_in[7];
    const float* Wp     = (const float*)d_in[8];
    const float* bp     = (const float*)d_in[9];
    const float* Wt1    = (const float*)d_in[10];
    const float* bt1    = (const float*)d_in[11];
    const float* Wt2    = (const float*)d_in[12];
    const float* bt2    = (const float*)d_in[13];
    const float* Wd1    = (const float*)d_in[14];
    const float* bd1    = (const float*)d_in[15];
    const float* Wd2    = (const float*)d_in[16];
    const float* bd2    = (const float*)d_in[17];

    float* ws = (float*)d_ws;
    float* cond     = ws;                    // 16384
    float* qk       = cond + 16384;          // 16384
    float* h        = qk + 16384;            // 16384
    float* q        = h + 16384;             // 16384
    float* wout     = q + 16384;             // 4096
    float* vsum     = wout + 4096;           // 16384
    float* ve       = vsum + 16384;          // 16384
    float* ne       = ve + 16384;            // 16384
    float* p_part   = ne + 16384;            // 65536
    float* tif_best = p_part + 65536;        // 2097152 (8 MB)
    ushort* Abf     = (ushort*)(tif_best + 2097152);  // 4 MB
    ushort* Wb      = Abf + 2097152;         // 1 MB
    unsigned* bar   = (unsigned*)(Wb + 524288);  // 4 KB barrier area
    float* out = (float*)d_out;

    hipMemsetAsync(bar, 0, 4096, stream);
    hipLaunchKernelGGL(mega, dim3(NBLK), dim3(256), 0, stream,
                       ts, pe, fusion, tif, x,
                       Wt1, bt1, Wt2, bt2, Wq, Wk, Wv, Wp, bp, Wd1,
                       cond, qk, h, q, wout, vsum, ve, ne,
                       tif_best, Abf, Wb, bar);
    hipLaunchKernelGGL(k4_mfma, dim3(32, 8), dim3(256), 0, stream,
                       Abf, Wb, Wd1, bd1, ne, Wd2, p_part);
    hipLaunchKernelGGL(k5_sort, dim3(BB), dim3(128), 0, stream,
                       p_part, wout, bd2, out);
}

// Round 6
// 187.438 us; speedup vs baseline: 7.1425x; 2.4911x over previous
//
#include <hip/hip_runtime.h>
#include <hip/hip_bf16.h>
#include <math.h>

// Problem: B=32, N=128, S=64, D=512
// Output: [B,N] f32, each row sorted descending.
// Structure (round 6): multi-launch (round-3 base, mega abandoned — grid
// barriers cost ~45us each from coherence-point poll contention).
// 10 launches: h, cond, q, qk, k2(+convWb), vsum, ve, ne, k4(+u), sort.

#define BB 32
#define NN 128
#define SS 64
#define DD 512

typedef __attribute__((ext_vector_type(8))) short short8;
typedef __attribute__((ext_vector_type(4))) float f32x4;

__device__ __forceinline__ ushort f2bf(float f) {
    unsigned u = __float_as_uint(f);
    unsigned r = (u + 0x7fffu + ((u >> 16) & 1u)) >> 16;
    return (ushort)r;
}

// Batched wave-dot: 4 rows of W (stride ldw) dotted with x (in regs xa/xb).
// All 8 row-loads issued before the serial shuffle reduces -> 8 float4 loads
// in flight per wave (latency hiding; single-dot version had only 2).
__device__ __forceinline__ void wave_dot512x4(
    const float* __restrict__ w, size_t ldw, float4 xa, float4 xb,
    int lane, float out[4]) {
    float4 ra[4], rb[4];
#pragma unroll
    for (int r = 0; r < 4; ++r) {
        const float4* row = reinterpret_cast<const float4*>(w + (size_t)r * ldw);
        ra[r] = row[lane * 2];
        rb[r] = row[lane * 2 + 1];
    }
#pragma unroll
    for (int r = 0; r < 4; ++r) {
        float s = ra[r].x * xa.x + ra[r].y * xa.y + ra[r].z * xa.z + ra[r].w * xa.w
                + rb[r].x * xb.x + rb[r].y * xb.y + rb[r].z * xb.z + rb[r].w * xb.w;
#pragma unroll
        for (int off = 32; off; off >>= 1) s += __shfl_xor(s, off);
        out[r] = s;
    }
}

// Batched matvec: Y[b][j] = act(W[j][:512] . X[b] + bias[j])
// grid (R/16, B), block 256 (4 waves x 4 rows each).
// mode 0: X = Xa[b] ; mode 1: X = pe[ts[b]] ; mode 2: X = Xa[b] + Xb[b]
__global__ __launch_bounds__(256) void bmv(
    const float* __restrict__ W, int ldw, const float* __restrict__ bias,
    const float* __restrict__ Xa, const float* __restrict__ Xb,
    const int* __restrict__ ts, const float* __restrict__ pe,
    float* __restrict__ Y, int R, int act, int mode) {
    __shared__ __align__(16) float xl[DD];
    int b = blockIdx.y, tid = threadIdx.x, lane = tid & 63, wave = tid >> 6;
    const float* src = (mode == 1) ? (pe + (size_t)ts[b] * DD) : (Xa + (size_t)b * DD);
    if (mode == 2) {
        const float* s2 = Xb + (size_t)b * DD;
        for (int i = tid; i < DD; i += 256) xl[i] = src[i] + s2[i];
    } else {
        for (int i = tid; i < DD; i += 256) xl[i] = src[i];
    }
    __syncthreads();
    float4 xa = reinterpret_cast<const float4*>(xl)[lane * 2];
    float4 xb = reinterpret_cast<const float4*>(xl)[lane * 2 + 1];
    int j0 = blockIdx.x * 16 + wave * 4;
    float s[4];
    wave_dot512x4(W + (size_t)j0 * ldw, ldw, xa, xb, lane, s);
    if (lane < 4) {
        int j = j0 + lane;
        float v = s[lane];
        if (bias) v += bias[j];
        if (act == 1) v = v / (1.f + expf(-v));  // silu
        Y[(size_t)b * R + j] = v;
    }
}

// qk[b][c] = sum_j q[b][j] * Wk[j][c]   (transposed matvec)
__global__ __launch_bounds__(256) void k_qk(
    const float* __restrict__ Wk, const float* __restrict__ q,
    float* __restrict__ qk) {
    __shared__ __align__(16) float ql[DD];
    __shared__ float part[4][64];
    int b = blockIdx.y, c0 = blockIdx.x * 64;
    int tid = threadIdx.x, lane = tid & 63, wave = tid >> 6;
    for (int i = tid; i < DD; i += 256) ql[i] = q[(size_t)b * DD + i];
    __syncthreads();
    float p = 0.f;
    for (int j = wave * 128; j < wave * 128 + 128; ++j)
        p += ql[j] * Wk[(size_t)j * DD + c0 + lane];
    part[wave][lane] = p;
    __syncthreads();
    if (tid < 64)
        qk[(size_t)b * DD + c0 + tid] =
            part[0][tid] + part[1][tid] + part[2][tid] + part[3][tid];
}

// K2: per (b,n): sim over S (4-row batched loads), argmax, gather best row
// (f32 + bf16), raw score. Blocks < 1024 also convert Wd1 right half to bf16.
__global__ __launch_bounds__(256) void k2_sim(
    const float* __restrict__ fusion, const float* __restrict__ tif,
    const float* __restrict__ x, const float* __restrict__ qk,
    const float* __restrict__ Wd1, ushort* __restrict__ Wb,
    float* __restrict__ tif_best, ushort* __restrict__ abf,
    float* __restrict__ score) {
    __shared__ __align__(16) float fb[DD];
    __shared__ float bv_s[4];
    __shared__ int bi_s[4];
    __shared__ int bidx_s;
    __shared__ float dred[4];
    int bn = blockIdx.x, b = bn >> 7;
    int tid = threadIdx.x, lane = tid & 63, wave = tid >> 6;

    // convWb prologue: 1024 blocks x 256 thr x 2 elems = 524288 elems
    if (bn < 1024) {
        int idx = (bn * 256 + tid) * 2;
        int r = idx >> 9, k = idx & 511;
        float2 v = *reinterpret_cast<const float2*>(Wd1 + (size_t)r * 1024 + 512 + k);
        ushort2 o = {f2bf(v.x), f2bf(v.y)};
        *reinterpret_cast<ushort2*>(Wb + (size_t)r * 512 + k) = o;
    }

    for (int i = tid; i < DD; i += 256) fb[i] = fusion[(size_t)b * DD + i];
    __syncthreads();
    float4 xa = reinterpret_cast<const float4*>(fb)[lane * 2];
    float4 xb = reinterpret_cast<const float4*>(fb)[lane * 2 + 1];
    const float* base = tif + (size_t)bn * SS * DD;
    float bv = -INFINITY;
    int bi = 0;
    for (int s0 = wave * 16; s0 < wave * 16 + 16; s0 += 4) {
        float sv[4];
        wave_dot512x4(base + (size_t)s0 * DD, DD, xa, xb, lane, sv);
#pragma unroll
        for (int r = 0; r < 4; ++r)
            if (sv[r] > bv) { bv = sv[r]; bi = s0 + r; }  // strict >: first max
    }
    if (lane == 0) { bv_s[wave] = bv; bi_s[wave] = bi; }
    __syncthreads();
    if (tid == 0) {
        float v = bv_s[0]; int i0 = bi_s[0];
        for (int w = 1; w < 4; w++)
            if (bv_s[w] > v) { v = bv_s[w]; i0 = bi_s[w]; }  // waves ascend in s
        bidx_s = i0;
    }
    __syncthreads();
    const float* src = base + (size_t)bidx_s * DD;
    const float* qkb = qk + (size_t)b * DD;
    float local = 0.f;
    for (int i = tid; i < DD; i += 256) {
        float vv = src[i];
        tif_best[(size_t)bn * DD + i] = vv;
        abf[(size_t)bn * DD + i] = f2bf(vv);
        local += vv * qkb[i];
    }
#pragma unroll
    for (int off = 32; off; off >>= 1) local += __shfl_xor(local, off);
    if (lane == 0) dred[wave] = local;
    __syncthreads();
    if (tid == 0) score[bn] = dred[0] + dred[1] + dred[2] + dred[3] + x[bn];
}

// vsum (softmax fused, computed redundantly per block). grid (2, B), block 256.
__global__ __launch_bounds__(256) void k_vsum(
    const float* __restrict__ score, const float* __restrict__ tif_best,
    const float* __restrict__ cond,
    float* __restrict__ wout, float* __restrict__ vsum) {
    __shared__ float wl[NN];
    __shared__ float redm[2], reds[2];
    int b = blockIdx.y, tid = threadIdx.x, lane = tid & 63, wave = tid >> 6;
    float v = 0.f;
    if (tid < NN) {
        v = score[b * NN + tid];
        float m = v;
#pragma unroll
        for (int off = 32; off; off >>= 1) m = fmaxf(m, __shfl_xor(m, off));
        if (lane == 0) redm[wave] = m;
    }
    __syncthreads();
    float m = fmaxf(redm[0], redm[1]);
    if (tid < NN) {
        float e = expf(v - m);
        wl[tid] = e;
        float s = e;
#pragma unroll
        for (int off = 32; off; off >>= 1) s += __shfl_xor(s, off);
        if (lane == 0) reds[wave] = s;
    }
    __syncthreads();
    float inv = 1.f / (reds[0] + reds[1]);
    if (blockIdx.x == 0 && tid < NN) wout[b * NN + tid] = wl[tid] * inv;
    int d = blockIdx.x * 256 + tid;
    const float* base = tif_best + (size_t)b * NN * DD + d;
    float s = 0.f;
#pragma unroll 8
    for (int n = 0; n < NN; n++) s += wl[n] * base[(size_t)n * DD];
    vsum[(size_t)b * DD + d] = s * inv + cond[(size_t)b * DD + d];
}

// K4: bf16 MFMA GEMM C[4096,1024] = Abf[4096,512] x Wb^T, fused u + relu + Wd2.
// Prologue computes this block's 128-row u-slice (overlapped with stage-0
// global_load_lds). Tile 128x128, BK=64, 4 waves, both-sides XOR swizzle.
__global__ __launch_bounds__(256) void k4_mfma(
    const ushort* __restrict__ Abf, const ushort* __restrict__ Wb,
    const float* __restrict__ Wd1, const float* __restrict__ bd1,
    const float* __restrict__ ne, const float* __restrict__ Wd2,
    float* __restrict__ p_part) {
    __shared__ ushort aS[128 * 64];  // 16 KB
    __shared__ ushort bS[128 * 64];
    __shared__ __align__(16) float nel[DD];
    __shared__ float uloc[128];
    int tid = threadIdx.x, l = tid & 63, w = tid >> 6;
    int m0 = blockIdx.x * 128, n0 = blockIdx.y * 128;
    int b = blockIdx.x;  // BM=128 == N rows per batch
    int wm = w >> 1, wn = w & 1;

    for (int i = tid; i < DD; i += 256) nel[i] = ne[(size_t)b * DD + i];
    __syncthreads();
    float4 na = reinterpret_cast<const float4*>(nel)[l * 2];
    float4 nb = reinterpret_cast<const float4*>(nel)[l * 2 + 1];

#define STAGE(K0)                                                              \
    {                                                                          \
        _Pragma("unroll") for (int i = 0; i < 4; ++i) {                        \
            int L = i * 4096 + w * 1024 + l * 16;                              \
            int row = L >> 7;                                                  \
            int bo = L & 127;                                                  \
            int sb = bo ^ ((row & 7) << 4);                                    \
            const ushort* ga = Abf + (size_t)(m0 + row) * DD + (K0) + (sb >> 1); \
            const ushort* gb = Wb + (size_t)(n0 + row) * DD + (K0) + (sb >> 1);  \
            __builtin_amdgcn_global_load_lds(                                  \
                (const __attribute__((address_space(1))) void*)ga,             \
                (__attribute__((address_space(3))) void*)(aS + i * 2048 + w * 512), \
                16, 0, 0);                                                     \
            __builtin_amdgcn_global_load_lds(                                  \
                (const __attribute__((address_space(1))) void*)gb,             \
                (__attribute__((address_space(3))) void*)(bS + i * 2048 + w * 512), \
                16, 0, 0);                                                     \
        }                                                                      \
    }

    STAGE(0);
    // u-prologue overlaps stage-0: u[r] = Wd1_a[n0+r].ne[b] + bd1[n0+r]
    for (int j0 = 0; j0 < 32; j0 += 4) {
        int r = w * 32 + j0;
        float s[4];
        wave_dot512x4(Wd1 + (size_t)(n0 + r) * 1024, 1024, na, nb, l, s);
        if (l < 4) uloc[r + l] = s[l] + bd1[n0 + r + l];
    }
    __syncthreads();

    f32x4 acc[4][4];
#pragma unroll
    for (int i = 0; i < 4; i++)
#pragma unroll
        for (int j = 0; j < 4; j++) acc[i][j] = (f32x4){0.f, 0.f, 0.f, 0.f};

    for (int k0 = 0; k0 < DD; k0 += 64) {
#pragma unroll
        for (int kk = 0; kk < 2; ++kk) {
            short8 af[4], bf[4];
#pragma unroll
            for (int f = 0; f < 4; ++f) {
                int ra = wm * 64 + f * 16 + (l & 15);
                int boa = (((l >> 4) * 16 + kk * 64)) ^ ((ra & 7) << 4);
                af[f] = *reinterpret_cast<const short8*>(&aS[ra * 64 + (boa >> 1)]);
                int rb = wn * 64 + f * 16 + (l & 15);
                int bob = (((l >> 4) * 16 + kk * 64)) ^ ((rb & 7) << 4);
                bf[f] = *reinterpret_cast<const short8*>(&bS[rb * 64 + (bob >> 1)]);
            }
#pragma unroll
            for (int fm = 0; fm < 4; ++fm)
#pragma unroll
                for (int fn = 0; fn < 4; ++fn)
                    acc[fm][fn] = __builtin_amdgcn_mfma_f32_16x16x32_bf16(
                        af[fm], bf[fn], acc[fm][fn], 0, 0, 0);
        }
        __syncthreads();
        if (k0 + 64 < DD) {
            STAGE(k0 + 64);
            __syncthreads();
        }
    }
#undef STAGE
#pragma unroll
    for (int fm = 0; fm < 4; ++fm) {
#pragma unroll
        for (int reg = 0; reg < 4; ++reg) {
            float pp = 0.f;
#pragma unroll
            for (int fn = 0; fn < 4; ++fn) {
                int rl = wn * 64 + fn * 16 + (l & 15);
                float hh = acc[fm][fn][reg] + uloc[rl];
                if (hh > 0.f) pp += Wd2[n0 + rl] * hh;
            }
#pragma unroll
            for (int off = 1; off < 16; off <<= 1) pp += __shfl_xor(pp, off);
            if ((l & 15) == 0) {
                int m = m0 + wm * 64 + fm * 16 + (l >> 4) * 4 + reg;
                p_part[(size_t)m * 16 + blockIdx.y * 2 + wn] = pp;
            }
        }
    }
}

// K5: p = sum(p_part) + bd2 + w; bitonic sort 128 descending per b.
__global__ __launch_bounds__(128) void k5_sort(
    const float* __restrict__ p_part, const float* __restrict__ wout,
    const float* __restrict__ bd2, float* __restrict__ out) {
    __shared__ float v[NN];
    int b = blockIdx.x, tid = threadIdx.x;
    int bn = b * NN + tid;
    float s = bd2[0] + wout[bn];
#pragma unroll
    for (int c = 0; c < 16; c++) s += p_part[(size_t)bn * 16 + c];
    v[tid] = s;
    __syncthreads();
    for (int k = 2; k <= NN; k <<= 1) {
        for (int j = k >> 1; j > 0; j >>= 1) {
            int ixj = tid ^ j;
            if (ixj > tid) {
                float a = v[tid], bb2 = v[ixj];
                bool desc = (tid & k) == 0;
                if (desc ? (a < bb2) : (a > bb2)) { v[tid] = bb2; v[ixj] = a; }
            }
            __syncthreads();
        }
    }
    out[bn] = v[tid];
}

extern "C" void kernel_launch(void* const* d_in, const int* in_sizes, int n_in,
                              void* d_out, int out_size, void* d_ws, size_t ws_size,
                              hipStream_t stream) {
    const float* x      = (const float*)d_in[0];
    const int*   ts     = (const int*)d_in[1];
    const float* fusion = (const float*)d_in[2];
    const float* tif    = (const float*)d_in[3];
    const float* pe     = (const float*)d_in[4];
    const float* Wq     = (const float*)d_in[5];
    const float* Wk     = (const float*)d_in[6];
    const float* Wv     = (const float*)d_in[7];
    const float* Wp     = (const float*)d_in[8];
    const float* bp     = (const float*)d_in[9];
    const float* Wt1    = (const float*)d_in[10];
    const float* bt1    = (const float*)d_in[11];
    const float* Wt2    = (const float*)d_in[12];
    const float* bt2    = (const float*)d_in[13];
    const float* Wd1    = (const float*)d_in[14];
    const float* bd1    = (const float*)d_in[15];
    const float* Wd2    = (const float*)d_in[16];
    const float* bd2    = (const float*)d_in[17];

    float* ws = (float*)d_ws;
    float* cond     = ws;                    // 16384
    float* qk       = cond + 16384;          // 16384
    float* h        = qk + 16384;            // 16384
    float* q        = h + 16384;             // 16384
    float* score    = q + 16384;             // 4096
    float* wout     = score + 4096;          // 4096
    float* vsum     = wout + 4096;           // 16384
    float* ve       = vsum + 16384;          // 16384
    float* ne       = ve + 16384;            // 16384
    float* p_part   = ne + 16384;            // 65536
    float* tif_best = p_part + 65536;        // 2097152 (8 MB)
    ushort* Abf     = (ushort*)(tif_best + 2097152);  // 4 MB
    ushort* Wb      = Abf + 2097152;         // 1 MB
    float* out = (float*)d_out;

    // cond chain (grid-parallel over rows x batch)
    hipLaunchKernelGGL(bmv, dim3(32, BB), dim3(256), 0, stream,
                       Wt1, DD, bt1, nullptr, nullptr, ts, pe, h, DD, 1, 1);
    hipLaunchKernelGGL(bmv, dim3(32, BB), dim3(256), 0, stream,
                       Wt2, DD, bt2, h, nullptr, nullptr, nullptr, cond, DD, 0, 0);
    hipLaunchKernelGGL(bmv, dim3(32, BB), dim3(256), 0, stream,
                       Wq, DD, nullptr, fusion, cond, nullptr, nullptr, q, DD, 0, 2);
    hipLaunchKernelGGL(k_qk, dim3(8, BB), dim3(256), 0, stream, Wk, q, qk);

    // the 537MB streamer (+ convWb prologue)
    hipLaunchKernelGGL(k2_sim, dim3(BB * NN), dim3(256), 0, stream,
                       fusion, tif, x, qk, Wd1, Wb, tif_best, Abf, score);

    // attention chain
    hipLaunchKernelGGL(k_vsum, dim3(2, BB), dim3(256), 0, stream,
                       score, tif_best, cond, wout, vsum);
    hipLaunchKernelGGL(bmv, dim3(32, BB), dim3(256), 0, stream,
                       Wv, DD, nullptr, vsum, nullptr, nullptr, nullptr, ve, DD, 0, 0);
    hipLaunchKernelGGL(bmv, dim3(32, BB), dim3(256), 0, stream,
                       Wp, DD, bp, ve, nullptr, nullptr, nullptr, ne, DD, 0, 0);

    // decode GEMM (MFMA, u folded) + sort
    hipLaunchKernelGGL(k4_mfma, dim3(32, 8), dim3(256), 0, stream,
                       Abf, Wb, Wd1, bd1, ne, Wd2, p_part);
    hipLaunchKernelGGL(k5_sort, dim3(BB), dim3(128), 0, stream,
                       p_part, wout, bd2, out);
}